// Round 5
// baseline (203.888 us; speedup 1.0000x reference)
//
#include <hip/hip_runtime.h>

#define BN_EPS 1e-3f

using bfrag  = __attribute__((ext_vector_type(8))) short;  // 8 bf16 (4 VGPRs)
using f32x4v = __attribute__((ext_vector_type(4))) float;

__device__ __forceinline__ unsigned short f2bf(float f) {
    union { float f; unsigned u; } v; v.f = f;
    unsigned r = v.u + 0x7FFFu + ((v.u >> 16) & 1u);   // RNE
    return (unsigned short)(r >> 16);
}

// ---------------------------------------------------------------------------
// One prep kernel:
//  range A: vf   [N,16] fp32 -> xb0 [(N+1),16] bf16 (row N = zeros)
//  range B: feat2[N,16] fp32 -> xb2 [N,16]     bf16
//  range C: W0/W1 [27,16,16] -> Wb0/Wb1 MFMA B-frag order (14 steps)
//  range D: Wobo [16,16]     -> Wb2 B-frag (K=16 padded to 32)
// ---------------------------------------------------------------------------
__global__ __launch_bounds__(256)
void prep_kernel(const float* __restrict__ vf, const float* __restrict__ feat2,
                 const float* __restrict__ W0, const float* __restrict__ W1,
                 const float* __restrict__ Wobo,
                 unsigned short* __restrict__ xb0, unsigned short* __restrict__ xb2,
                 unsigned short* __restrict__ Wb0, unsigned short* __restrict__ Wb1,
                 unsigned short* __restrict__ Wb2, int N)
{
    int t = blockIdx.x * 256 + threadIdx.x;
    int TA = 2 * (N + 1), TB = 2 * N;
    unsigned short tmp[8];
    if (t < TA) {                         // xb0
        int n = t >> 1, h = t & 1;
        if (n < N) {
            const float* yr = vf + (size_t)n * 16 + h * 8;
#pragma unroll
            for (int j = 0; j < 8; ++j) tmp[j] = f2bf(yr[j]);
        } else {
#pragma unroll
            for (int j = 0; j < 8; ++j) tmp[j] = 0;
        }
        *(int4*)(xb0 + (size_t)n * 16 + h * 8) = *(int4*)tmp;
        return;
    }
    t -= TA;
    if (t < TB) {                         // xb2
        int n = t >> 1, h = t & 1;
        const float* yr = feat2 + (size_t)n * 16 + h * 8;
#pragma unroll
        for (int j = 0; j < 8; ++j) tmp[j] = f2bf(yr[j]);
        *(int4*)(xb2 + (size_t)n * 16 + h * 8) = *(int4*)tmp;
        return;
    }
    t -= TB;
    if (t < 2 * 14 * 64) {                // Wb0 / Wb1
        int w = t >= 896;
        int l = t - w * 896;
        int s = l >> 6, lane = l & 63;
        int q = lane >> 4, n = lane & 15;
        int tap = 2 * s + (q >> 1);
        int cb  = (q & 1) * 8;
        const float* W = w ? W1 : W0;
        unsigned short* Wb = w ? Wb1 : Wb0;
#pragma unroll
        for (int j = 0; j < 8; ++j)
            tmp[j] = (tap < 27) ? f2bf(W[((size_t)(tap * 16 + cb + j)) * 16 + n]) : 0;
        *(int4*)(Wb + (size_t)l * 8) = *(int4*)tmp;
        return;
    }
    t -= 2 * 14 * 64;
    if (t < 64) {                         // Wb2: B[k=q*8+j][n], k>=16 -> 0
        int q = t >> 4, n = t & 15;
#pragma unroll
        for (int j = 0; j < 8; ++j)
            tmp[j] = (q < 2) ? f2bf(Wobo[(size_t)(q * 8 + j) * 16 + n]) : 0;
        *(int4*)(Wb2 + (size_t)t * 8) = *(int4*)tmp;
    }
}

// ---------------------------------------------------------------------------
// MFMA submanifold conv + fused BN stats. Wave = 16 voxels x 16 outputs,
// K=432 padded to 448 = 14 steps of 16x16x32 bf16. Stats: per-lane partial
// over C rows -> shfl_xor(16,32) -> LDS atomics -> 32 global atomics/block.
// ---------------------------------------------------------------------------
__global__ __launch_bounds__(256)
void conv_mfma_kernel(const unsigned short* __restrict__ xb,  // [(N+1),16] bf16
                      const unsigned short* __restrict__ Wb,  // [14*64*8] bf16
                      const int* __restrict__ nbr,            // [N,27]
                      float* __restrict__ y,                  // [N,16] pre-BN
                      float* __restrict__ stats,              // [32] sum|sumsq
                      int N)
{
    __shared__ float sred[32];
    if (threadIdx.x < 32) sred[threadIdx.x] = 0.f;
    __syncthreads();

    int gwave = (blockIdx.x * 256 + threadIdx.x) >> 6;
    int lane  = threadIdx.x & 63;
    int base  = gwave * 16;
    int q = lane >> 4, m = lane & 15;
    int c0   = (q & 1) * 8;
    int tpar = q >> 1;
    int vox  = base + m;

    f32x4v acc = {0.f, 0.f, 0.f, 0.f};
    if (base < N) {
        const int* nr = nbr + (size_t)vox * 27;
        int idx[14];
#pragma unroll
        for (int s = 0; s < 14; ++s) {
            int tap = 2 * s + tpar;
            int id  = (vox < N && tap < 27) ? nr[tap] : -1;
            idx[s]  = (id >= 0) ? id : N;     // row N = zeros
        }
#pragma unroll
        for (int s = 0; s < 14; ++s) {
            if (__ballot(idx[s] != N) == 0ull) continue;
            bfrag a = *(const bfrag*)(xb + (size_t)idx[s] * 16 + c0);
            bfrag b = *(const bfrag*)(Wb + ((size_t)s * 64 + lane) * 8);
            acc = __builtin_amdgcn_mfma_f32_16x16x32_bf16(a, b, acc, 0, 0, 0);
        }
        // C/D: col = lane&15 = out channel, row = q*4+i
        int o = lane & 15;
#pragma unroll
        for (int i = 0; i < 4; ++i) {
            int row = base + q * 4 + i;
            if (row < N) y[(size_t)row * 16 + o] = acc[i];
        }
        // fused stats (rows >= N have zero A rows -> acc = 0, safe)
        float s  = acc[0] + acc[1] + acc[2] + acc[3];
        float qq = acc[0] * acc[0] + acc[1] * acc[1] + acc[2] * acc[2] + acc[3] * acc[3];
        s  += __shfl_xor(s, 16);  s  += __shfl_xor(s, 32);
        qq += __shfl_xor(qq, 16); qq += __shfl_xor(qq, 32);
        if (lane < 16) {
            atomicAdd(&sred[lane], s);
            atomicAdd(&sred[16 + lane], qq);
        }
    }
    __syncthreads();
    if (threadIdx.x < 32)
        atomicAdd(&stats[threadIdx.x], sred[threadIdx.x]);
}

// ---------------------------------------------------------------------------
// xb1[n] = bf16(relu(y0[n]*sc+sh)), row N = zeros. Thread = 8 channels.
// ---------------------------------------------------------------------------
__global__ __launch_bounds__(256)
void bnrelu_cvt_kernel(const float* __restrict__ y0, const float* __restrict__ stats,
                       const float* __restrict__ g, const float* __restrict__ b,
                       float invN, unsigned short* __restrict__ xb, int N)
{
    int t = blockIdx.x * 256 + threadIdx.x;
    if (t >= (N + 1) * 2) return;
    int n = t >> 1, h = t & 1;
    unsigned short tmp[8];
    if (n < N) {
        const float* yr = y0 + (size_t)n * 16 + h * 8;
#pragma unroll
        for (int j = 0; j < 8; ++j) {
            int c = h * 8 + j;
            float mu  = stats[c] * invN;
            float var = stats[16 + c] * invN - mu * mu;
            float sc  = g[c] * rsqrtf(var + BN_EPS);
            float v   = fmaxf(fmaf(yr[j], sc, b[c] - mu * sc), 0.f);
            tmp[j] = f2bf(v);
        }
    } else {
#pragma unroll
        for (int j = 0; j < 8; ++j) tmp[j] = 0;
    }
    *(int4*)(xb + (size_t)n * 16 + h * 8) = *(int4*)tmp;
}

// ---------------------------------------------------------------------------
// t2 = feat2 @ Wobo + bobo via MFMA: wave = 16 rows, one 16x16x32 step
// (K=16, upper half zero-padded via q>=2 -> zero A/B frags).
// ---------------------------------------------------------------------------
__global__ __launch_bounds__(256)
void t2_gemm_kernel(const unsigned short* __restrict__ xb2,  // [N,16] bf16
                    const unsigned short* __restrict__ Wb2,  // [64*8] bf16
                    const float* __restrict__ bobo,
                    float* __restrict__ t2buf, int N)
{
    int gwave = (blockIdx.x * 256 + threadIdx.x) >> 6;
    int lane  = threadIdx.x & 63;
    int base  = gwave * 16;
    if (base >= N) return;
    int q = lane >> 4, m = lane & 15;
    int vox = base + m;

    bfrag a = {0, 0, 0, 0, 0, 0, 0, 0};
    if (q < 2 && vox < N)
        a = *(const bfrag*)(xb2 + (size_t)vox * 16 + q * 8);
    bfrag b = *(const bfrag*)(Wb2 + (size_t)lane * 8);
    f32x4v acc = {0.f, 0.f, 0.f, 0.f};
    acc = __builtin_amdgcn_mfma_f32_16x16x32_bf16(a, b, acc, 0, 0, 0);

    int o = lane & 15;
    float bo = bobo[o];
#pragma unroll
    for (int i = 0; i < 4; ++i) {
        int row = base + q * 4 + i;
        if (row < N) t2buf[(size_t)row * 16 + o] = acc[i] + bo;
    }
}

// First tensor: relu(bn1(y1)) -> plain stores (seg[0:N] strictly increasing
// => injective; slots without an h row stay zero from the memset).
__global__ __launch_bounds__(256)
void scatter_h_kernel(const float* __restrict__ y1, const float* __restrict__ stats,
                      const float* __restrict__ g, const float* __restrict__ b,
                      float invN, const int* __restrict__ seg,
                      float* __restrict__ merged, int N)
{
    int r = blockIdx.x * 256 + threadIdx.x;
    if (r >= N) return;
    float sc[16], sh[16];
#pragma unroll
    for (int c = 0; c < 16; ++c) {
        float mu  = stats[c] * invN;
        float var = stats[16 + c] * invN - mu * mu;
        float s   = g[c] * rsqrtf(var + BN_EPS);
        sc[c] = s;
        sh[c] = b[c] - mu * s;
    }
    const float4* yr = (const float4*)(y1 + (size_t)r * 16);
    float4* mo = (float4*)(merged + (size_t)seg[r] * 16);
#pragma unroll
    for (int i = 0; i < 4; ++i) {
        float4 v = yr[i];
        float4 rr;
        rr.x = fmaxf(fmaf(v.x, sc[i * 4 + 0], sh[i * 4 + 0]), 0.f);
        rr.y = fmaxf(fmaf(v.y, sc[i * 4 + 1], sh[i * 4 + 1]), 0.f);
        rr.z = fmaxf(fmaf(v.z, sc[i * 4 + 2], sh[i * 4 + 2]), 0.f);
        rr.w = fmaxf(fmaf(v.w, sc[i * 4 + 3], sh[i * 4 + 3]), 0.f);
        mo[i] = rr;
    }
}

// Second tensor merge: seg[N:2N] non-decreasing -> equal slots are adjacent
// runs. Run leader sums precomputed t2 rows (float4) and RMW-adds into
// merged. Must run AFTER scatter_h (h plain-stores, t2 accumulates).
__global__ __launch_bounds__(256)
void t2_merge_kernel(const float* __restrict__ t2buf, const int* __restrict__ seg,
                     float* __restrict__ merged, int N)
{
    int r = blockIdx.x * 256 + threadIdx.x;
    if (r >= N) return;
    const int* seg2 = seg + N;
    int s = seg2[r];
    if (r > 0 && seg2[r - 1] == s) return;   // not a run leader
    const float4* tr = (const float4*)(t2buf + (size_t)r * 16);
    float4 v0 = tr[0], v1 = tr[1], v2 = tr[2], v3 = tr[3];
    for (int i = r + 1; i < N && seg2[i] == s; ++i) {
        const float4* ti = (const float4*)(t2buf + (size_t)i * 16);
        float4 a0 = ti[0], a1 = ti[1], a2 = ti[2], a3 = ti[3];
        v0.x += a0.x; v0.y += a0.y; v0.z += a0.z; v0.w += a0.w;
        v1.x += a1.x; v1.y += a1.y; v1.z += a1.z; v1.w += a1.w;
        v2.x += a2.x; v2.y += a2.y; v2.z += a2.z; v2.w += a2.w;
        v3.x += a3.x; v3.y += a3.y; v3.z += a3.z; v3.w += a3.w;
    }
    float4* mo4 = (float4*)(merged + (size_t)s * 16);
    float4 m0 = mo4[0], m1 = mo4[1], m2 = mo4[2], m3 = mo4[3];
    mo4[0] = make_float4(m0.x + v0.x, m0.y + v0.y, m0.z + v0.z, m0.w + v0.w);
    mo4[1] = make_float4(m1.x + v1.x, m1.y + v1.y, m1.z + v1.z, m1.w + v1.w);
    mo4[2] = make_float4(m2.x + v2.x, m2.y + v2.y, m2.z + v2.z, m2.w + v2.w);
    mo4[3] = make_float4(m3.x + v3.x, m3.y + v3.y, m3.z + v3.z, m3.w + v3.w);
}

// out[u,:] = merged[u,:16] @ Wf + bf. Thread = 4 cols x 16 rows; Wf block in
// 16 float4 regs; depth-1 row prefetch; coalesced float4 stores.
__global__ __launch_bounds__(256)
void final_gemm_kernel(const float* __restrict__ merged, const float* __restrict__ Wf,
                       const float* __restrict__ bf, float* __restrict__ out, int U)
{
    int jg = threadIdx.x & 31;
    int ub = threadIdx.x >> 5;
    int u0 = (blockIdx.x * 8 + ub) * 16;
    if (u0 >= U) return;
    float4 wf[16];
#pragma unroll
    for (int c = 0; c < 16; ++c) wf[c] = *(const float4*)(Wf + c * 128 + jg * 4);
    float4 bj = *(const float4*)(bf + jg * 4);
    int uend = min(u0 + 16, U);

    const float4* mr = (const float4*)(merged + (size_t)u0 * 16);
    float4 a0 = mr[0], a1 = mr[1], a2 = mr[2], a3 = mr[3];
#pragma unroll 1
    for (int u = u0; u < uend; ++u) {
        float4 c0 = a0, c1 = a1, c2 = a2, c3 = a3;
        if (u + 1 < uend) {
            const float4* nx = (const float4*)(merged + (size_t)(u + 1) * 16);
            a0 = nx[0]; a1 = nx[1]; a2 = nx[2]; a3 = nx[3];
        }
        float m[16];
        *(float4*)(m + 0)  = c0; *(float4*)(m + 4)  = c1;
        *(float4*)(m + 8)  = c2; *(float4*)(m + 12) = c3;
        float4 s = bj;
#pragma unroll
        for (int c = 0; c < 16; ++c) {
            s.x = fmaf(m[c], wf[c].x, s.x);
            s.y = fmaf(m[c], wf[c].y, s.y);
            s.z = fmaf(m[c], wf[c].z, s.z);
            s.w = fmaf(m[c], wf[c].w, s.w);
        }
        *(float4*)(out + (size_t)u * 128 + jg * 4) = s;
    }
}

extern "C" void kernel_launch(void* const* d_in, const int* in_sizes, int n_in,
                              void* d_out, int out_size, void* d_ws, size_t ws_size,
                              hipStream_t stream)
{
    const float* vf    = (const float*)d_in[0];
    const float* feat2 = (const float*)d_in[1];
    const float* W0    = (const float*)d_in[2];
    const float* g0    = (const float*)d_in[3];
    const float* b0    = (const float*)d_in[4];
    const float* W1    = (const float*)d_in[5];
    const float* g1    = (const float*)d_in[6];
    const float* b1    = (const float*)d_in[7];
    const float* Wobo  = (const float*)d_in[8];
    const float* bobo  = (const float*)d_in[9];
    const float* Wf    = (const float*)d_in[10];
    const float* bf    = (const float*)d_in[11];
    const int*   nbr   = (const int*)d_in[12];
    const int*   seg   = (const int*)d_in[13];

    int N = in_sizes[0] / 16;   // 100000
    int U = out_size / 128;     // num_segments

    float* out = (float*)d_out;
    float* ws  = (float*)d_ws;

    // Workspace layout (float units). merged+stats contiguous -> ONE memset.
    float* y0     = ws;                                   // N*16
    float* y1     = y0 + (size_t)N * 16;                  // N*16
    float* t2buf  = y1 + (size_t)N * 16;                  // N*16
    float* merged = t2buf + (size_t)N * 16;               // U*16
    float* stats  = merged + (size_t)U * 16;              // 64 (stats0|stats1)
    unsigned short* xb0 = (unsigned short*)(stats + 64);  // (N+1)*16 bf16
    unsigned short* xb1 = xb0 + (size_t)(N + 1) * 16;     // (N+1)*16 bf16
    unsigned short* xb2 = xb1 + (size_t)(N + 1) * 16;     // N*16 bf16
    unsigned short* Wb0 = xb2 + (size_t)N * 16;           // 14*64*8 bf16
    unsigned short* Wb1 = Wb0 + 14 * 64 * 8;              // 14*64*8 bf16
    unsigned short* Wb2 = Wb1 + 14 * 64 * 8;              // 64*8 bf16

    hipMemsetAsync(merged, 0, ((size_t)U * 16 + 64) * sizeof(float), stream);

    float invN  = 1.f / (float)N;
    int thrPrep = 2 * (N + 1) + 2 * N + 2 * 14 * 64 + 64;
    int gbPrep  = (thrPrep + 255) / 256;
    int gbConv  = (N + 63) / 64;               // 4 waves x 16 voxels per block
    int gbCvt   = ((N + 1) * 2 + 255) / 256;
    int gbN     = (N + 255) / 256;

    prep_kernel<<<gbPrep, 256, 0, stream>>>(vf, feat2, W0, W1, Wobo,
                                            xb0, xb2, Wb0, Wb1, Wb2, N);
    conv_mfma_kernel<<<gbConv, 256, 0, stream>>>(xb0, Wb0, nbr, y0, stats, N);
    bnrelu_cvt_kernel<<<gbCvt, 256, 0, stream>>>(y0, stats, g0, b0, invN, xb1, N);
    conv_mfma_kernel<<<gbConv, 256, 0, stream>>>(xb1, Wb1, nbr, y1, stats + 32, N);
    t2_gemm_kernel<<<gbConv, 256, 0, stream>>>(xb2, Wb2, bobo, t2buf, N);
    scatter_h_kernel<<<gbN, 256, 0, stream>>>(y1, stats + 32, g1, b1, invN, seg, merged, N);
    t2_merge_kernel<<<gbN, 256, 0, stream>>>(t2buf, seg, merged, N);
    final_gemm_kernel<<<(U + 127) / 128, 256, 0, stream>>>(merged, Wf, bf, out, U);
}